// Round 6
// baseline (14.237 us; speedup 1.0000x reference)
//
#include <hip/hip_runtime.h>
#include <math.h>

#define TPB 256
#define TOK 16
#define TILE (TPB * TOK)        // 4096 tokens per block
#define HALO 14                 // MAX_SPAN_WIDTH - 1
#define WIN (TOK + 2 * HALO)    // 44-value per-thread window
#define NEGINF (-10000.0f)
#define SENT (-1.0e30f)         // out-of-row sentinel (invalid spans lose every max)
#define LDSF 4128               // TILE+2*HALO=4124, padded to 32-float multiple

// Bank swizzle for 16-float (64B) lane stride: XOR bank-quad bits (f>>2)&7
// with block bits (f>>4)&7. Uniform within any aligned quad -> aligned
// float2/float4 ops stay contiguous; spreads the wave's accesses evenly
// (8 lanes per bank-quad = the b128 minimum).
__device__ __forceinline__ int swz16(int f) { return f ^ (((f >> 4) & 7) << 2); }
// XOR constant for the 16-float block containing f (valid for all g in
// [f & ~15, (f & ~15)+16): swz16(g) == g ^ blkX(f))
__device__ __forceinline__ int blkX(int f) { return ((f >> 4) & 7) << 2; }

// A[] holds (in place) sparse-table level K = 2^floor(log2 W) when called.
// Q[u] = min of width-W span starting at window pos 15-W+u, u = 0..W+14;
// token k (window pos 14+k, k=0..15) needs max over Q[k..k+W-1].
// W>=8: 2 groups of 8 tokens, anchors u=7,15 -> shared suffix/prefix scans.
// W in 4..7: 4 groups of 4, anchors u=3,7,11,15. All indices compile-time.
template <int W>
__device__ __forceinline__ void do_width(const float (&A)[WIN], float wt,
                                         float (&b)[TOK]) {
  constexpr int K = (W < 4) ? 2 : ((W < 8) ? 4 : 8);
  constexpr int S0 = (HALO + 1) - W;  // 15 - W
  constexpr int NQ = W + TOK - 1;     // W + 15
  float Q[NQ];
#pragma unroll
  for (int u = 0; u < NQ; ++u) {
    if constexpr (W == K)
      Q[u] = A[S0 + u];
    else
      Q[u] = fminf(A[S0 + u], A[S0 + u + (W - K)]);
  }
  float m[TOK];
  if constexpr (W == 2) {
#pragma unroll
    for (int k = 0; k < TOK; ++k) m[k] = fmaxf(Q[k], Q[k + 1]);
  } else if constexpr (W == 3) {
#pragma unroll
    for (int k = 0; k < TOK; ++k)
      m[k] = fmaxf(fmaxf(Q[k], Q[k + 1]), Q[k + 2]);  // v_max3
  } else if constexpr (W < 8) {
#pragma unroll
    for (int gp = 0; gp < TOK / 4; ++gp) {  // anchors at 4*gp+3
      const int a = 4 * gp + 3;
      float S[4];
      S[3] = Q[a];
      S[2] = fmaxf(Q[a - 1], S[3]);
      S[1] = fmaxf(Q[a - 2], S[2]);
      S[0] = fmaxf(Q[a - 3], S[1]);
      float T[W];
      T[0] = Q[a];
#pragma unroll
      for (int jj = 1; jj < W; ++jj) T[jj] = fmaxf(T[jj - 1], Q[a + jj]);
#pragma unroll
      for (int d = 0; d < 4; ++d) m[4 * gp + d] = fmaxf(S[d], T[d + W - 4]);
    }
  } else {
#pragma unroll
    for (int gp = 0; gp < TOK / 8; ++gp) {  // anchors at 8*gp+7
      const int a = 8 * gp + 7;
      float S[8];
      S[7] = Q[a];
#pragma unroll
      for (int d = 6; d >= 0; --d) S[d] = fmaxf(Q[8 * gp + d], S[d + 1]);
      float T[W];
      T[0] = Q[a];
#pragma unroll
      for (int jj = 1; jj < W; ++jj) T[jj] = fmaxf(T[jj - 1], Q[a + jj]);
#pragma unroll
      for (int d = 0; d < 8; ++d) m[8 * gp + d] = fmaxf(S[d], T[d + W - 8]);
    }
  }
#pragma unroll
  for (int k = 0; k < TOK; ++k) b[k] = fmaxf(b[k], m[k] * wt);
}

__global__ __launch_bounds__(TPB, 2) void span_kernel(
    const float *__restrict__ ts, const int *__restrict__ mask,
    const float *__restrict__ wlog, const float *__restrict__ gamma_p,
    float *__restrict__ out, int N, int tiles_per_row) {
  __shared__ __align__(16) float sm[LDSF];
  __shared__ float swt[15];  // 14 softmax weights + gamma at [14]
  const int tid = threadIdx.x;
  const int row = blockIdx.x / tiles_per_row;
  const int t0 = (blockIdx.x % tiles_per_row) * TILE;
  const float *tsrow = ts + (size_t)row * N;
  const int *mrow = mask + (size_t)row * N;

  // ---- staging: 16 tokens/thread (4x int4 + 4x float4) ----
  const int j = tid * TOK;  // 0..4080, 16-float aligned
  const int g = t0 + j;
  int4 mv[4];
  float4 tv[4];
#pragma unroll
  for (int q = 0; q < 4; ++q) {
    mv[q] = *reinterpret_cast<const int4 *>(&mrow[g + 4 * q]);
    tv[q] = *reinterpret_cast<const float4 *>(&tsrow[g + 4 * q]);
  }
  float w[TOK];
#pragma unroll
  for (int q = 0; q < 4; ++q) {
    w[4 * q + 0] = mv[q].x ? tv[q].x : NEGINF;
    w[4 * q + 1] = mv[q].y ? tv[q].y : NEGINF;
    w[4 * q + 2] = mv[q].z ? tv[q].z : NEGINF;
    w[4 * q + 3] = mv[q].w ? tv[q].w : NEGINF;
  }
  {
    // logical LDS positions j+14 .. j+29 (f0 = HALO + j)
    const int X0 = blkX(j);       // covers j+14, j+15
    const int X1 = blkX(j + 16);  // covers j+16 .. j+29
    float2 a;
    a.x = w[0];
    a.y = w[1];
    *reinterpret_cast<float2 *>(&sm[(j + 14) ^ X0]) = a;
    float4 c;
    c.x = w[2]; c.y = w[3]; c.z = w[4]; c.w = w[5];
    *reinterpret_cast<float4 *>(&sm[(j + 16) ^ X1]) = c;
    c.x = w[6]; c.y = w[7]; c.z = w[8]; c.w = w[9];
    *reinterpret_cast<float4 *>(&sm[(j + 20) ^ X1]) = c;
    c.x = w[10]; c.y = w[11]; c.z = w[12]; c.w = w[13];
    *reinterpret_cast<float4 *>(&sm[(j + 24) ^ X1]) = c;
    a.x = w[14];
    a.y = w[15];
    *reinterpret_cast<float2 *>(&sm[(j + 28) ^ X1]) = a;
  }
  // halo: lanes 0..27 fill left(14)+right(14) edges (out-of-row -> sentinel)
  if (tid < 2 * HALO) {
    const int hk = (tid < HALO) ? tid : (TILE + tid);  // logical sm index
    const int tok = t0 - HALO + hk;                    // global token
    float v = SENT;
    if (tok >= 0 && tok < N) v = mrow[tok] ? tsrow[tok] : NEGINF;
    sm[swz16(hk)] = v;
  }
  // softmax of width logits: ONE thread (serial order bit-matches np ref)
  if (tid == TPB - 1) {
    float e[15], mx = -3.4e38f;
#pragma unroll
    for (int i = 0; i < 15; ++i) {
      e[i] = wlog[i];
      mx = fmaxf(mx, e[i]);
    }
    float ssum = 0.0f;
#pragma unroll
    for (int i = 0; i < 15; ++i) {
      e[i] = expf(e[i] - mx);
      ssum += e[i];
    }
    const float inv = 1.0f / ssum;
#pragma unroll
    for (int i = 0; i < 14; ++i) swt[i] = e[i] * inv;
    swt[14] = *gamma_p;
  }
  __syncthreads();

  // ---- per-thread 44-value window (11x ds_read_b128, even bank spread) ----
  float A[WIN];
  {
    const int X0 = blkX(j), X1 = blkX(j + 16), X2 = blkX(j + 32);
#pragma unroll
    for (int q = 0; q < WIN / 4; ++q) {
      const int X = (q < 4) ? X0 : ((q < 8) ? X1 : X2);
      const float4 v =
          *reinterpret_cast<const float4 *>(&sm[(j + 4 * q) ^ X]);
      A[4 * q + 0] = v.x;
      A[4 * q + 1] = v.y;
      A[4 * q + 2] = v.z;
      A[4 * q + 3] = v.w;
    }
  }
  // width-1 boost: the masked scores themselves (before A is overwritten)
  float b[TOK];
#pragma unroll
  for (int k = 0; k < TOK; ++k) b[k] = A[HALO + k];

  // ---- in-place sparse table: ascending update never reads a clobbered slot
#pragma unroll
  for (int x = 0; x < WIN - 1; ++x) A[x] = fminf(A[x], A[x + 1]);  // P2
  do_width<2>(A, swt[0], b);
  do_width<3>(A, swt[1], b);

#pragma unroll
  for (int x = 0; x < WIN - 3; ++x) A[x] = fminf(A[x], A[x + 2]);  // P4
  do_width<4>(A, swt[2], b);
  do_width<5>(A, swt[3], b);
  do_width<6>(A, swt[4], b);
  do_width<7>(A, swt[5], b);

#pragma unroll
  for (int x = 0; x < WIN - 7; ++x) A[x] = fminf(A[x], A[x + 4]);  // P8
  do_width<8>(A, swt[6], b);
  do_width<9>(A, swt[7], b);
  do_width<10>(A, swt[8], b);
  do_width<11>(A, swt[9], b);
  do_width<12>(A, swt[10], b);
  do_width<13>(A, swt[11], b);
  do_width<14>(A, swt[12], b);
  do_width<15>(A, swt[13], b);

  // ---- output: raw scores kept in registers from staging ----
  const float gamma = swt[14];
  float *orow = out + (size_t)row * N + g;
#pragma unroll
  for (int q = 0; q < 4; ++q) {
    float4 o;
    o.x = tv[q].x + gamma * b[4 * q + 0];
    o.y = tv[q].y + gamma * b[4 * q + 1];
    o.z = tv[q].z + gamma * b[4 * q + 2];
    o.w = tv[q].w + gamma * b[4 * q + 3];
    *reinterpret_cast<float4 *>(orow + 4 * q) = o;
  }
}

extern "C" void kernel_launch(void *const *d_in, const int *in_sizes, int n_in,
                              void *d_out, int out_size, void *d_ws,
                              size_t ws_size, hipStream_t stream) {
  const float *ts = (const float *)d_in[0];
  const int *mask = (const int *)d_in[1];
  const float *wlog = (const float *)d_in[2];
  const float *gamma_p = (const float *)d_in[3];
  float *out = (float *)d_out;
  const int N = 8192;          // fixed problem shape (B=256, N=8192)
  const int B = in_sizes[0] / N;
  const int tiles = N / TILE;  // 2
  span_kernel<<<dim3(B * tiles), dim3(TPB), 0, stream>>>(ts, mask, wlog,
                                                         gamma_p, out, N,
                                                         tiles);
}

// Round 7
// 13.441 us; speedup vs baseline: 1.0592x; 1.0592x over previous
//
#include <hip/hip_runtime.h>
#include <math.h>

#define TPB 256
#define TOK 8
#define TILE (TPB * TOK)        // 2048 tokens per block
#define HALO 14                 // MAX_SPAN_WIDTH - 1
#define WIN (TOK + 2 * HALO)    // 36-value per-thread window
#define NEGINF (-10000.0f)
#define SENT (-1.0e30f)         // out-of-row sentinel (invalid spans lose every max)
#define LDSF 2080               // TILE+2*HALO=2076, padded

// Bank-conflict swizzle: XOR bank-quad bits (f>>2)&7 with bits (f>>5)&7.
// Uniform within any aligned quad -> aligned float2/float4 ops stay
// contiguous & aligned. At TOK=8 the lane stride is 32 floats, which
// unswizzled puts all lanes on the same 4 banks.
__device__ __forceinline__ int swz(int f) { return f ^ (((f >> 5) & 7) << 2); }

// A[] holds (in place) sparse-table level K = 2^floor(log2 W) when called.
// Q[u] = min of the width-W span starting at window pos 15-W+u, u=0..W+6;
// token k (window pos 14+k, k=0..7) needs max over Q[k..k+W-1].
// Widths >=8: all 8 intervals contain anchor 7 -> shared prefix/suffix.
// Widths 4..7: two 4-token groups anchored at 3 and 7. All indices static.
template <int W>
__device__ __forceinline__ void do_width(const float (&A)[WIN], float wt,
                                         float (&b)[TOK]) {
  constexpr int K = (W < 4) ? 2 : ((W < 8) ? 4 : 8);
  constexpr int S0 = (HALO + 1) - W;  // 15 - W
  constexpr int NQ = W + TOK - 1;     // W + 7
  float Q[NQ];
#pragma unroll
  for (int u = 0; u < NQ; ++u) {
    if constexpr (W == K)
      Q[u] = A[S0 + u];
    else
      Q[u] = fminf(A[S0 + u], A[S0 + u + (W - K)]);
  }
  float m[TOK];
  if constexpr (W == 2) {
#pragma unroll
    for (int k = 0; k < TOK; ++k) m[k] = fmaxf(Q[k], Q[k + 1]);
  } else if constexpr (W == 3) {
#pragma unroll
    for (int k = 0; k < TOK; ++k)
      m[k] = fmaxf(fmaxf(Q[k], Q[k + 1]), Q[k + 2]);  // v_max3
  } else if constexpr (W < 8) {
    // tokens 0..3 anchored at Q[3], tokens 4..7 anchored at Q[7]
    float SA[4];
    SA[3] = Q[3];
#pragma unroll
    for (int k = 2; k >= 0; --k) SA[k] = fmaxf(Q[k], SA[k + 1]);
    float TA[W];
    TA[0] = Q[3];
#pragma unroll
    for (int j = 1; j < W; ++j) TA[j] = fmaxf(TA[j - 1], Q[3 + j]);
#pragma unroll
    for (int k = 0; k < 4; ++k) m[k] = fmaxf(SA[k], TA[k + W - 4]);
    float SB[4];
    SB[3] = Q[7];
#pragma unroll
    for (int k = 2; k >= 0; --k) SB[k] = fmaxf(Q[4 + k], SB[k + 1]);
    float TB[W];
    TB[0] = Q[7];
#pragma unroll
    for (int j = 1; j < W; ++j) TB[j] = fmaxf(TB[j - 1], Q[7 + j]);
#pragma unroll
    for (int k = 0; k < 4; ++k) m[4 + k] = fmaxf(SB[k], TB[k + W - 4]);
  } else {
    float S[8];
    S[7] = Q[7];
#pragma unroll
    for (int k = 6; k >= 0; --k) S[k] = fmaxf(Q[k], S[k + 1]);
    float T[W];
    T[0] = Q[7];
#pragma unroll
    for (int j = 1; j < W; ++j) T[j] = fmaxf(T[j - 1], Q[7 + j]);
#pragma unroll
    for (int k = 0; k < TOK; ++k) m[k] = fmaxf(S[k], T[k + W - 8]);
  }
#pragma unroll
  for (int k = 0; k < TOK; ++k) b[k] = fmaxf(b[k], m[k] * wt);
}

__global__ __launch_bounds__(TPB, 4) void span_kernel(
    const float *__restrict__ ts, const int *__restrict__ mask,
    const float *__restrict__ wlog, const float *__restrict__ gamma_p,
    float *__restrict__ out, int N, int tiles_per_row) {
  __shared__ __align__(16) float sm[LDSF];
  __shared__ float swt[15];  // 14 softmax weights + gamma at [14]
  const int tid = threadIdx.x;
  const int row = blockIdx.x / tiles_per_row;
  const int t0 = (blockIdx.x % tiles_per_row) * TILE;
  const float *tsrow = ts + (size_t)row * N;
  const int *mrow = mask + (size_t)row * N;

  // ---- staging: 8 tokens/thread (2x int4 + 2x float4) ----
  const int j = tid * TOK;  // 0..2040
  const int g = t0 + j;
  const int4 mv0 = *reinterpret_cast<const int4 *>(&mrow[g]);
  const int4 mv1 = *reinterpret_cast<const int4 *>(&mrow[g + 4]);
  const float4 tv0 = *reinterpret_cast<const float4 *>(&tsrow[g]);
  const float4 tv1 = *reinterpret_cast<const float4 *>(&tsrow[g + 4]);
  {
    const int f0 = HALO + j;  // %8 == 6
    float2 a;                 // f0 .. f0+1 (quad pos 2,3)
    a.x = mv0.x ? tv0.x : NEGINF;
    a.y = mv0.y ? tv0.y : NEGINF;
    float4 c;                 // f0+2 .. f0+5 (quad-aligned)
    c.x = mv0.z ? tv0.z : NEGINF;
    c.y = mv0.w ? tv0.w : NEGINF;
    c.z = mv1.x ? tv1.x : NEGINF;
    c.w = mv1.y ? tv1.y : NEGINF;
    float2 d;                 // f0+6 .. f0+7 (quad pos 0,1)
    d.x = mv1.z ? tv1.z : NEGINF;
    d.y = mv1.w ? tv1.w : NEGINF;
    *reinterpret_cast<float2 *>(&sm[swz(f0)]) = a;
    *reinterpret_cast<float4 *>(&sm[swz(f0 + 2)]) = c;
    *reinterpret_cast<float2 *>(&sm[swz(f0 + 6)]) = d;
  }
  // halo: lanes 0..27 fill left(14)+right(14) edges (out-of-row -> sentinel)
  if (tid < 2 * HALO) {
    const int hk = (tid < HALO) ? tid : (TILE + tid);  // logical sm index
    const int tok = t0 - HALO + hk;                    // global token
    float v = SENT;
    if (tok >= 0 && tok < N) v = mrow[tok] ? tsrow[tok] : NEGINF;
    sm[swz(hk)] = v;
  }
  // softmax of width logits: ONE thread (serial order bit-matches np ref)
  if (tid == TPB - 1) {
    float e[15], mx = -3.4e38f;
#pragma unroll
    for (int i = 0; i < 15; ++i) {
      e[i] = wlog[i];
      mx = fmaxf(mx, e[i]);
    }
    float ssum = 0.0f;
#pragma unroll
    for (int i = 0; i < 15; ++i) {
      e[i] = expf(e[i] - mx);
      ssum += e[i];
    }
    const float inv = 1.0f / ssum;
#pragma unroll
    for (int i = 0; i < 14; ++i) swt[i] = e[i] * inv;
    swt[14] = *gamma_p;
  }
  __syncthreads();

  // ---- per-thread 36-value window (9x conflict-free ds_read_b128) ----
  float A[WIN];
#pragma unroll
  for (int q = 0; q < WIN / 4; ++q) {
    const float4 v = *reinterpret_cast<const float4 *>(&sm[swz(j + 4 * q)]);
    A[4 * q + 0] = v.x;
    A[4 * q + 1] = v.y;
    A[4 * q + 2] = v.z;
    A[4 * q + 3] = v.w;
  }
  // width-1 boost: the masked scores themselves (before A is overwritten)
  float b[TOK];
#pragma unroll
  for (int k = 0; k < TOK; ++k) b[k] = A[HALO + k];

  // ---- in-place sparse table: ascending update never reads a clobbered slot
#pragma unroll
  for (int x = 0; x < WIN - 1; ++x) A[x] = fminf(A[x], A[x + 1]);  // P2
  do_width<2>(A, swt[0], b);
  do_width<3>(A, swt[1], b);

#pragma unroll
  for (int x = 0; x < WIN - 3; ++x) A[x] = fminf(A[x], A[x + 2]);  // P4
  do_width<4>(A, swt[2], b);
  do_width<5>(A, swt[3], b);
  do_width<6>(A, swt[4], b);
  do_width<7>(A, swt[5], b);

#pragma unroll
  for (int x = 0; x < WIN - 7; ++x) A[x] = fminf(A[x], A[x + 4]);  // P8
  do_width<8>(A, swt[6], b);
  do_width<9>(A, swt[7], b);
  do_width<10>(A, swt[8], b);
  do_width<11>(A, swt[9], b);
  do_width<12>(A, swt[10], b);
  do_width<13>(A, swt[11], b);
  do_width<14>(A, swt[12], b);
  do_width<15>(A, swt[13], b);

  // ---- output: raw scores kept in registers from staging ----
  const float gamma = swt[14];
  float4 o0, o1;
  o0.x = tv0.x + gamma * b[0];
  o0.y = tv0.y + gamma * b[1];
  o0.z = tv0.z + gamma * b[2];
  o0.w = tv0.w + gamma * b[3];
  o1.x = tv1.x + gamma * b[4];
  o1.y = tv1.y + gamma * b[5];
  o1.z = tv1.z + gamma * b[6];
  o1.w = tv1.w + gamma * b[7];
  float *orow = out + (size_t)row * N + g;
  *reinterpret_cast<float4 *>(orow) = o0;
  *reinterpret_cast<float4 *>(orow + 4) = o1;
}

extern "C" void kernel_launch(void *const *d_in, const int *in_sizes, int n_in,
                              void *d_out, int out_size, void *d_ws,
                              size_t ws_size, hipStream_t stream) {
  const float *ts = (const float *)d_in[0];
  const int *mask = (const int *)d_in[1];
  const float *wlog = (const float *)d_in[2];
  const float *gamma_p = (const float *)d_in[3];
  float *out = (float *)d_out;
  const int N = 8192;          // fixed problem shape (B=256, N=8192)
  const int B = in_sizes[0] / N;
  const int tiles = N / TILE;  // 4
  span_kernel<<<dim3(B * tiles), dim3(TPB), 0, stream>>>(ts, mask, wlog,
                                                         gamma_p, out, N,
                                                         tiles);
}